// Round 3
// baseline (149.441 us; speedup 1.0000x reference)
//
#include <hip/hip_runtime.h>
#include <hip/hip_bf16.h>

#define BB 2
#define NN 384
#define DIM 256
#define HID 128
#define ROWS (BB*NN)   // 768

typedef __attribute__((ext_vector_type(8))) short bf16x8;
typedef __attribute__((ext_vector_type(4))) float f32x4;

static __device__ __forceinline__ unsigned int f2bf(float f) {
    unsigned int u = __builtin_bit_cast(unsigned int, f);
    return (u + 0x7FFFu + ((u >> 16) & 1u)) >> 16;   // RNE bf16 bits in low 16
}

// ---- qkv = x @ qkv_w + qkv_b (f32), written TRANSPOSED [c][row]; + w2->bf16 prep ----
__global__ __launch_bounds__(256) void qkv_gemm(const float* __restrict__ x,
        const float* __restrict__ w, const float* __restrict__ bias,
        float* __restrict__ qt, float* __restrict__ kt, float* __restrict__ vt,
        const float* __restrict__ w2, unsigned short* __restrict__ w2t) {
    __shared__ float xs[4][DIM];
    const int r0 = blockIdx.x * 4;
    const int t = threadIdx.x;

    // fused w2 [128][256] f32 -> w2t [256][128] bf16 (first 128 blocks)
    if (blockIdx.x < 128) {
        int g = blockIdx.x * 256 + t;         // g = h*256 + c
        w2t[(g & 255) * HID + (g >> 8)] = (unsigned short)f2bf(w2[g]);
    }

    #pragma unroll
    for (int i = 0; i < 4; ++i) xs[i][t] = x[(r0 + i) * DIM + t];
    __syncthreads();
    float acc[4][3];
    #pragma unroll
    for (int r = 0; r < 4; ++r) { acc[r][0]=0.f; acc[r][1]=0.f; acc[r][2]=0.f; }
    for (int k = 0; k < DIM; k += 4) {
        float4 xv[4];
        #pragma unroll
        for (int r = 0; r < 4; ++r) xv[r] = *(const float4*)&xs[r][k];
        #pragma unroll
        for (int kk = 0; kk < 4; ++kk) {
            float w0 = w[(k+kk)*768 + t];
            float w1v = w[(k+kk)*768 + t + 256];
            float w2v = w[(k+kk)*768 + t + 512];
            #pragma unroll
            for (int r = 0; r < 4; ++r) {
                float xr = kk==0?xv[r].x : kk==1?xv[r].y : kk==2?xv[r].z : xv[r].w;
                acc[r][0] += xr*w0; acc[r][1] += xr*w1v; acc[r][2] += xr*w2v;
            }
        }
    }
    const float bq = bias[t], bk = bias[t+256], bv = bias[t+512];
    float4 qe = {acc[0][0]+bq, acc[1][0]+bq, acc[2][0]+bq, acc[3][0]+bq};
    float4 ke = {acc[0][1]+bk, acc[1][1]+bk, acc[2][1]+bk, acc[3][1]+bk};
    float4 ve = {acc[0][2]+bv, acc[1][2]+bv, acc[2][2]+bv, acc[3][2]+bv};
    *(float4*)&qt[t*ROWS + r0] = qe;
    *(float4*)&kt[t*ROWS + r0] = ke;
    *(float4*)&vt[t*ROWS + r0] = ve;
}

// ---------------- fused rel-pos MLP + per-channel online softmax ----------------
__global__ __launch_bounds__(256, 3) void attn_main(
        const float* __restrict__ qt,           // [DIM][ROWS]
        const float* __restrict__ kt,           // [DIM][ROWS]
        const float* __restrict__ vt,           // [DIM][ROWS]
        const float* __restrict__ pos,          // [ROWS][3]
        const unsigned char* __restrict__ mask, // [ROWS] (bool)
        const float* __restrict__ w1,           // [HID]
        const float* __restrict__ b1,           // [HID]
        const unsigned short* __restrict__ w2t, // [256][128] bf16, c-major
        const float* __restrict__ b2,           // [DIM]
        float* __restrict__ out_pre)            // [ROWS][DIM]
{
    __shared__ unsigned short hl[32][HID];  // swizzled 16B units: u' = u ^ ((j&7)<<1)
    __shared__ float w1s[HID], b1s[HID];

    const int tid = threadIdx.x;
    const int row = blockIdx.x;               // b*N + i
    const int b = row / NN;
    const int l = tid & 63;
    const int wv = tid >> 6;
    const int cbase = wv * 64;
    const int lc = l & 15, lr = l >> 4;

    if (tid < HID) { w1s[tid] = w1[tid]; b1s[tid] = b1[tid]; }

    // B fragments (w2) straight from global (L2-resident, one time)
    bf16x8 Bc[4][4];
    #pragma unroll
    for (int ct = 0; ct < 4; ++ct) {
        int c = cbase + ct * 16 + lc;
        #pragma unroll
        for (int kk = 0; kk < 4; ++kk) {
            int u = kk * 4 + lr;
            Bc[ct][kk] = *(const bf16x8*)(w2t + c * HID + u * 8);
        }
    }

    float kqv[4], b2v[4];
    #pragma unroll
    for (int ct = 0; ct < 4; ++ct) {
        int c = cbase + ct * 16 + lc;
        kqv[ct] = kt[c * ROWS + row];         // x_k[b,i,c]
        b2v[ct] = b2[c];
    }
    const float pix = pos[row*3+0], piy = pos[row*3+1], piz = pos[row*3+2];
    const bool mi = mask[row] != 0;

    float m[4], s[4], o[4];
    #pragma unroll
    for (int ct = 0; ct < 4; ++ct) { m[ct] = -INFINITY; s[ct] = 0.f; o[ct] = 0.f; }

    for (int jb = 0; jb < NN; jb += 32) {
        __syncthreads();   // hl consumed by previous iteration / w1s ready
        // stage h tile: h[j][k] = relu(d_ij * w1[k] + b1[k]) as bf16
        #pragma unroll
        for (int it = 0; it < 2; ++it) {
            int item = tid + (it << 8);       // 0..511
            int jl = item >> 4;               // 0..31
            int u  = item & 15;               // k-group of 8
            int j  = jb + jl;
            float dx = pix - pos[(b*NN + j)*3 + 0];
            float dy = piy - pos[(b*NN + j)*3 + 1];
            float dz = piz - pos[(b*NN + j)*3 + 2];
            float sq = dx*dx + dy*dy + dz*dz;
            float d  = sq > 0.f ? sqrtf(sq) : 0.f;
            float4 wa = *(const float4*)&w1s[u*8];
            float4 wb = *(const float4*)&w1s[u*8+4];
            float4 ba = *(const float4*)&b1s[u*8];
            float4 bb = *(const float4*)&b1s[u*8+4];
            float h0 = fmaxf(d*wa.x + ba.x, 0.f), h1 = fmaxf(d*wa.y + ba.y, 0.f);
            float h2 = fmaxf(d*wa.z + ba.z, 0.f), h3 = fmaxf(d*wa.w + ba.w, 0.f);
            float h4 = fmaxf(d*wb.x + bb.x, 0.f), h5 = fmaxf(d*wb.y + bb.y, 0.f);
            float h6 = fmaxf(d*wb.z + bb.z, 0.f), h7 = fmaxf(d*wb.w + bb.w, 0.f);
            uint4 pkt;
            pkt.x = f2bf(h0) | (f2bf(h1) << 16);
            pkt.y = f2bf(h2) | (f2bf(h3) << 16);
            pkt.z = f2bf(h4) | (f2bf(h5) << 16);
            pkt.w = f2bf(h6) | (f2bf(h7) << 16);
            int up = u ^ ((jl & 7) << 1);
            *(uint4*)&hl[jl][up * 8] = pkt;
        }
        __syncthreads();

        #pragma unroll
        for (int jt = 0; jt < 2; ++jt) {
            bf16x8 Af[4];
            #pragma unroll
            for (int kk = 0; kk < 4; ++kk) {
                int jl = jt * 16 + lc;
                int u  = kk * 4 + lr;
                int up = u ^ ((jl & 7) << 1);
                Af[kk] = *(const bf16x8*)&hl[jl][up * 8];
            }
            const int jrow0 = jb + jt * 16 + (lr << 2);   // batch-local j
            const int jg0   = b * NN + jrow0;             // global row
            #pragma unroll
            for (int ct = 0; ct < 4; ++ct) {
                f32x4 acc = {0.f, 0.f, 0.f, 0.f};
                #pragma unroll
                for (int kk = 0; kk < 4; ++kk)
                    acc = __builtin_amdgcn_mfma_f32_16x16x32_bf16(Af[kk], Bc[ct][kk], acc, 0, 0, 0);

                const int c = cbase + ct * 16 + lc;
                const float4 q4 = *(const float4*)(qt + c * ROWS + jg0);
                const float4 v4 = *(const float4*)(vt + c * ROWS + jg0);
                float logit[4], vval[4];
                #pragma unroll
                for (int r = 0; r < 4; ++r) {
                    float rp = acc[r] + b2v[ct];                 // SCALE = 1
                    float qv = r==0?q4.x : r==1?q4.y : r==2?q4.z : q4.w;
                    float vv = r==0?v4.x : r==1?v4.y : r==2?v4.z : v4.w;
                    logit[r] = fmaf(kqv[ct], qv, rp);
                    vval[r]  = vv + rp;
                }
                if (mi) {   // pair mask = mask_i & mask_j (all-false in practice)
                    #pragma unroll
                    for (int r = 0; r < 4; ++r)
                        if (mask[jg0 + r]) logit[r] = -INFINITY;
                }
                float tmax = fmaxf(fmaxf(logit[0], logit[1]), fmaxf(logit[2], logit[3]));
                if (tmax > m[ct]) {           // defer-rescale: rare after warmup
                    float sc = __expf(m[ct] - tmax);
                    s[ct] *= sc; o[ct] *= sc; m[ct] = tmax;
                }
                #pragma unroll
                for (int r = 0; r < 4; ++r) {
                    float p = __expf(logit[r] - m[ct]);
                    s[ct] += p;
                    o[ct] += p * vval[r];
                }
            }
        }
    }

    // merge per-thread (m,s,o) across the 4 j-lane-groups, then write
    #pragma unroll
    for (int ct = 0; ct < 4; ++ct) {
        float mm = m[ct], ss = s[ct], oo = o[ct];
        #pragma unroll
        for (int d = 16; d <= 32; d <<= 1) {
            float mo = __shfl_xor(mm, d, 64);
            float so = __shfl_xor(ss, d, 64);
            float og = __shfl_xor(oo, d, 64);
            float mn = fmaxf(mm, mo);
            float ea = __expf(mm - mn), eb = __expf(mo - mn);
            ss = ss * ea + so * eb;
            oo = oo * ea + og * eb;
            mm = mn;
        }
        if (l < 16) out_pre[row * DIM + cbase + ct * 16 + l] = oo / ss;
    }
}

// ---------------- out = out_pre @ out_w + out_b (f32) ----------------
__global__ __launch_bounds__(256) void out_gemm(const float* __restrict__ a,
        const float* __restrict__ w, const float* __restrict__ bias,
        float* __restrict__ out) {
    __shared__ float as[4][DIM];
    const int r0 = blockIdx.x * 4;
    const int t = threadIdx.x;
    #pragma unroll
    for (int i = 0; i < 4; ++i) as[i][t] = a[(r0 + i) * DIM + t];
    __syncthreads();
    float acc[4] = {0.f, 0.f, 0.f, 0.f};
    for (int k = 0; k < DIM; k += 4) {
        float4 xv[4];
        #pragma unroll
        for (int r = 0; r < 4; ++r) xv[r] = *(const float4*)&as[r][k];
        #pragma unroll
        for (int kk = 0; kk < 4; ++kk) {
            float wv = w[(k+kk)*DIM + t];
            #pragma unroll
            for (int r = 0; r < 4; ++r) {
                float xr = kk==0?xv[r].x : kk==1?xv[r].y : kk==2?xv[r].z : xv[r].w;
                acc[r] += xr * wv;
            }
        }
    }
    #pragma unroll
    for (int r = 0; r < 4; ++r) out[(r0+r)*DIM + t] = acc[r] + bias[t];
}

extern "C" void kernel_launch(void* const* d_in, const int* in_sizes, int n_in,
                              void* d_out, int out_size, void* d_ws, size_t ws_size,
                              hipStream_t stream) {
    const float* x      = (const float*)d_in[0];
    const float* pos    = (const float*)d_in[1];
    const unsigned char* mask = (const unsigned char*)d_in[2];
    const float* qkv_w  = (const float*)d_in[3];
    const float* qkv_b  = (const float*)d_in[4];
    const float* pm_w1  = (const float*)d_in[5];
    const float* pm_b1  = (const float*)d_in[6];
    const float* pm_w2  = (const float*)d_in[7];
    const float* pm_b2  = (const float*)d_in[8];
    const float* out_w  = (const float*)d_in[9];
    const float* out_b  = (const float*)d_in[10];
    float* out = (float*)d_out;

    char* ws = (char*)d_ws;
    float* qt           = (float*)(ws);                 // 256*768*4 = 786,432 B
    float* kt           = (float*)(ws +  786432);       // 786,432 B
    float* vt           = (float*)(ws + 1572864);       // 786,432 B
    float* out_pre      = (float*)(ws + 2359296);       // 786,432 B
    unsigned short* w2t = (unsigned short*)(ws + 3145728); // 65,536 B

    hipLaunchKernelGGL(qkv_gemm, dim3(ROWS/4), dim3(256), 0, stream,
                       x, qkv_w, qkv_b, qt, kt, vt, pm_w2, w2t);
    hipLaunchKernelGGL(attn_main, dim3(ROWS), dim3(256), 0, stream,
                       qt, kt, vt, pos, mask, pm_w1, pm_b1, w2t, pm_b2, out_pre);
    hipLaunchKernelGGL(out_gemm, dim3(ROWS/4), dim3(256), 0, stream, out_pre, out_w, out_b, out);
}